// Round 1
// baseline (269.655 us; speedup 1.0000x reference)
//
#include <hip/hip_runtime.h>

#define NSP 4096
#define HW 512
#define TEMP 0.08838834764831845f  // 128^-0.5

// ---------------- K0: zero the adjacency bitmask (ws is poisoned 0xAA) -----
__global__ void zero_mask(unsigned int* __restrict__ mask) {
    int i = blockIdx.x * blockDim.x + threadIdx.x;   // 131072 uint4 = 2 MB
    ((uint4*)mask)[i] = make_uint4(0u, 0u, 0u, 0u);
}

// ---------------- K1: build adjacency bitmask ------------------------------
// window (i,j), i,j in [0,510): labels seg[i..i+1][j..j+1]; connect (max,min)
__global__ void build_adj(const int* __restrict__ seg, unsigned int* __restrict__ mask) {
    int idx = blockIdx.x * blockDim.x + threadIdx.x;
    const int NW = 510 * 510;
    if (idx >= NW) return;
    int i = idx / 510, j = idx - i * 510;
    const int* r = seg + i * HW + j;
    int a = r[0], b = r[1], c = r[HW], d = r[HW + 1];
    int mx = max(max(a, b), max(c, d));
    int mn = min(min(a, b), min(c, d));
    if (mx == mn) return;                            // diagonal zeroed in ref
    atomicOr(&mask[mx * 128 + (mn >> 5)], 1u << (mn & 31));
    atomicOr(&mask[mn * 128 + (mx >> 5)], 1u << (mx & 31));
}

// ---------------- K2: packed QKV GEMM --------------------------------------
// x = spf^T (4096x128); only q head0 (cols 0..31), k head0 (128..159),
// v all (256..383) are needed. thread = (n, group-of-4-cols), 48 groups.
__global__ void qkv_gemm(const float* __restrict__ spf, const float* __restrict__ wqkv,
                         float* __restrict__ Q0, float* __restrict__ K0,
                         float* __restrict__ V) {
    int gid = blockIdx.x * blockDim.x + threadIdx.x;   // 4096*48
    int g = gid % 48;
    int n = gid / 48;
    int wcol;
    float* outp;
    if (g < 8)       { wcol = g * 4;              outp = Q0 + n * 32  + g * 4; }
    else if (g < 16) { wcol = 128 + (g - 8) * 4;  outp = K0 + n * 32  + (g - 8) * 4; }
    else             { wcol = 256 + (g - 16) * 4; outp = V  + n * 128 + (g - 16) * 4; }
    float4 acc = {0.f, 0.f, 0.f, 0.f};
    for (int d = 0; d < 128; ++d) {
        float x = spf[d * NSP + n];                  // x[n][d] = spf[d][n]
        float4 w = *(const float4*)(wqkv + d * 384 + wcol);
        acc.x += x * w.x; acc.y += x * w.y; acc.z += x * w.z; acc.w += x * w.w;
    }
    *(float4*)outp = acc;
}

// ---------------- K3: l2 normalize q0 / k0 rows ----------------------------
__global__ void l2norm_qk(float* __restrict__ Q0, float* __restrict__ K0) {
    int t = blockIdx.x * blockDim.x + threadIdx.x;   // 0..8191
    float* p = (t < NSP) ? (Q0 + t * 32) : (K0 + (t - NSP) * 32);
    float4* p4 = (float4*)p;
    float4 v[8];
    float s = 0.f;
#pragma unroll
    for (int i = 0; i < 8; ++i) {
        v[i] = p4[i];
        s += v[i].x * v[i].x + v[i].y * v[i].y + v[i].z * v[i].z + v[i].w * v[i].w;
    }
    float inv = 1.0f / fmaxf(sqrtf(s), 1e-12f);
#pragma unroll
    for (int i = 0; i < 8; ++i) {
        v[i].x *= inv; v[i].y *= inv; v[i].z *= inv; v[i].w *= inv;
        p4[i] = v[i];
    }
}

// ---------------- K4: sparse masked softmax-attention ----------------------
// one block (128 thr) per node n. Row max is exactly 1.0 (diagonal score);
// masked entries underflow to 0. out[n] = (V[n] + sum w_m V[m]) / (1 + sum w_m)
__global__ void __launch_bounds__(128) sparse_attn(
    const unsigned int* __restrict__ mask, const float* __restrict__ Q0,
    const float* __restrict__ K0, const float* __restrict__ V,
    float* __restrict__ out) {
    int n = blockIdx.x;
    int t = threadIdx.x;                             // 0..127
    __shared__ int   midx[NSP];
    __shared__ float wts[NSP];
    __shared__ int   cnt;
    __shared__ float q0s[32];
    if (t == 0) cnt = 0;
    if (t < 32) q0s[t] = Q0[n * 32 + t];
    __syncthreads();

    // phase 1: thread t scans mask word t (columns t*32 .. t*32+31)
    unsigned int w = mask[n * 128 + t];
    while (w) {
        int b = __ffs(w) - 1;
        w &= w - 1;
        int m = t * 32 + b;
        const float4* kp = (const float4*)(K0 + m * 32);
        float s = 0.f;
#pragma unroll
        for (int i = 0; i < 8; ++i) {
            float4 kv = kp[i];
            s += q0s[i * 4 + 0] * kv.x + q0s[i * 4 + 1] * kv.y +
                 q0s[i * 4 + 2] * kv.z + q0s[i * 4 + 3] * kv.w;
        }
        float wt = __expf(s * TEMP - 1.0f);
        int pos = atomicAdd(&cnt, 1);
        midx[pos] = m;
        wts[pos]  = wt;
    }
    __syncthreads();

    // phase 2: thread t owns channel t; coalesced V rows
    int c = cnt;
    float acc  = V[n * 128 + t];                     // diagonal, weight e^0 = 1
    float wsum = 1.0f;
    for (int e = 0; e < c; ++e) {
        float wt = wts[e];
        acc  += wt * V[midx[e] * 128 + t];
        wsum += wt;
    }
    out[n * 128 + t] = acc / wsum;
}

// ---------------- K5: out = attn_out @ w_out + b_out, stored TRANSPOSED ----
// finalT[c][n] so the gather reads one 16 KB L1-resident row per channel.
__global__ void out_gemm(const float* __restrict__ ain, const float* __restrict__ wout,
                         const float* __restrict__ bout, float* __restrict__ finalT) {
    int gid = blockIdx.x * blockDim.x + threadIdx.x; // 4096*32
    int g = gid & 31;                                // col group (4 cols)
    int n = gid >> 5;
    const float* arow = ain + n * 128;
    float4 acc = {0.f, 0.f, 0.f, 0.f};
    for (int d = 0; d < 128; ++d) {
        float a = arow[d];
        float4 w = *(const float4*)(wout + d * 128 + g * 4);
        acc.x += a * w.x; acc.y += a * w.y; acc.z += a * w.z; acc.w += a * w.w;
    }
    float4 b = *(const float4*)(bout + g * 4);
    int c = g * 4;
    finalT[(c + 0) * NSP + n] = acc.x + b.x;
    finalT[(c + 1) * NSP + n] = acc.y + b.y;
    finalT[(c + 2) * NSP + n] = acc.z + b.z;
    finalT[(c + 3) * NSP + n] = acc.w + b.w;
}

// ---------------- K6: pixel gather -----------------------------------------
// out[c][i][j] = finalT[c][seg[i][j]]; block = (pixgroup of 8192, channel c)
__global__ void gather_out(const float* __restrict__ finalT, const int* __restrict__ seg,
                           float* __restrict__ out) {
    int c = blockIdx.y;                              // 0..127
    int base = blockIdx.x * 8192;                    // 32 groups * 8192 = 262144
    const float* row = finalT + c * NSP;
    float* o = out + c * (HW * HW) + base;
    const int* s = seg + base;
    int t = threadIdx.x;
#pragma unroll 4
    for (int r = 0; r < 32; ++r) {
        int idx = r * 256 + t;
        o[idx] = row[s[idx]];
    }
}

extern "C" void kernel_launch(void* const* d_in, const int* in_sizes, int n_in,
                              void* d_out, int out_size, void* d_ws, size_t ws_size,
                              hipStream_t stream) {
    const float* spf  = (const float*)d_in[0];   // (128, 4096)
    const int*   seg  = (const int*)d_in[1];     // (512, 512)
    const float* wqkv = (const float*)d_in[2];   // (128, 384)
    const float* wout = (const float*)d_in[3];   // (128, 128)
    const float* bout = (const float*)d_in[4];   // (128,)
    float* out = (float*)d_out;                  // (1,128,512,512)

    char* ws = (char*)d_ws;                      // needs 9 MB
    unsigned int* mask = (unsigned int*)ws;                     // 2 MB
    float* Q0   = (float*)(ws + (2u << 20));                    // 512 KB
    float* K0   = (float*)(ws + (2u << 20) + (512u << 10));     // 512 KB
    float* V    = (float*)(ws + (3u << 20));                    // 2 MB
    float* aout = (float*)(ws + (5u << 20));                    // 2 MB
    float* fT   = (float*)(ws + (7u << 20));                    // 2 MB

    hipLaunchKernelGGL(zero_mask,  dim3(512),  dim3(256), 0, stream, mask);
    hipLaunchKernelGGL(build_adj,  dim3((510 * 510 + 255) / 256), dim3(256), 0, stream, seg, mask);
    hipLaunchKernelGGL(qkv_gemm,   dim3(768),  dim3(256), 0, stream, spf, wqkv, Q0, K0, V);
    hipLaunchKernelGGL(l2norm_qk,  dim3(32),   dim3(256), 0, stream, Q0, K0);
    hipLaunchKernelGGL(sparse_attn, dim3(4096), dim3(128), 0, stream, mask, Q0, K0, V, aout);
    hipLaunchKernelGGL(out_gemm,   dim3(512),  dim3(256), 0, stream, aout, wout, bout, fT);
    hipLaunchKernelGGL(gather_out, dim3(32, 128), dim3(256), 0, stream, fT, seg, out);
}

// Round 2
// 241.564 us; speedup vs baseline: 1.1163x; 1.1163x over previous
//
#include <hip/hip_runtime.h>

#define NSP 4096
#define HW 512
#define TEMP 0.08838834764831845f  // 128^-0.5
#define MAXE 768                   // max neighbors/node; measured degree ~127+-11

// ---------------- K0: zero the adjacency bitmask (ws is poisoned 0xAA) -----
__global__ void zero_mask(unsigned int* __restrict__ mask) {
    int i = blockIdx.x * blockDim.x + threadIdx.x;   // 131072 uint4 = 2 MB
    ((uint4*)mask)[i] = make_uint4(0u, 0u, 0u, 0u);
}

// ---------------- K1: build adjacency bitmask ------------------------------
// window (i,j), i,j in [0,510): labels seg[i..i+1][j..j+1]; connect (max,min)
__global__ void build_adj(const int* __restrict__ seg, unsigned int* __restrict__ mask) {
    int idx = blockIdx.x * blockDim.x + threadIdx.x;
    const int NW = 510 * 510;
    if (idx >= NW) return;
    int i = idx / 510, j = idx - i * 510;
    const int* r = seg + i * HW + j;
    int a = r[0], b = r[1], c = r[HW], d = r[HW + 1];
    int mx = max(max(a, b), max(c, d));
    int mn = min(min(a, b), min(c, d));
    if (mx == mn) return;                            // diagonal zeroed in ref
    atomicOr(&mask[mx * 128 + (mn >> 5)], 1u << (mn & 31));
    atomicOr(&mask[mn * 128 + (mx >> 5)], 1u << (mx & 31));
}

// ---------------- K2: packed QKV GEMM --------------------------------------
// x = spf^T (4096x128); only q head0 (cols 0..31), k head0 (128..159),
// v all (256..383) are needed. thread = (n, group-of-4-cols), 48 groups.
__global__ void qkv_gemm(const float* __restrict__ spf, const float* __restrict__ wqkv,
                         float* __restrict__ Q0, float* __restrict__ K0,
                         float* __restrict__ V) {
    int gid = blockIdx.x * blockDim.x + threadIdx.x;   // 4096*48
    int g = gid % 48;
    int n = gid / 48;
    int wcol;
    float* outp;
    if (g < 8)       { wcol = g * 4;              outp = Q0 + n * 32  + g * 4; }
    else if (g < 16) { wcol = 128 + (g - 8) * 4;  outp = K0 + n * 32  + (g - 8) * 4; }
    else             { wcol = 256 + (g - 16) * 4; outp = V  + n * 128 + (g - 16) * 4; }
    float4 acc = {0.f, 0.f, 0.f, 0.f};
#pragma unroll 8
    for (int d = 0; d < 128; ++d) {
        float x = spf[d * NSP + n];                  // x[n][d] = spf[d][n]
        float4 w = *(const float4*)(wqkv + d * 384 + wcol);
        acc.x += x * w.x; acc.y += x * w.y; acc.z += x * w.z; acc.w += x * w.w;
    }
    *(float4*)outp = acc;
}

// ---------------- K3: l2 normalize q0 / k0 rows ----------------------------
__global__ void l2norm_qk(float* __restrict__ Q0, float* __restrict__ K0) {
    int t = blockIdx.x * blockDim.x + threadIdx.x;   // 0..8191
    float* p = (t < NSP) ? (Q0 + t * 32) : (K0 + (t - NSP) * 32);
    float4* p4 = (float4*)p;
    float4 v[8];
    float s = 0.f;
#pragma unroll
    for (int i = 0; i < 8; ++i) {
        v[i] = p4[i];
        s += v[i].x * v[i].x + v[i].y * v[i].y + v[i].z * v[i].z + v[i].w * v[i].w;
    }
    float inv = 1.0f / fmaxf(sqrtf(s), 1e-12f);
#pragma unroll
    for (int i = 0; i < 8; ++i) {
        v[i].x *= inv; v[i].y *= inv; v[i].z *= inv; v[i].w *= inv;
        p4[i] = v[i];
    }
}

// ---------------- K4: sparse masked softmax-attention ----------------------
// one block (128 thr) per node n. Row max is exactly 1.0 (diagonal score);
// masked entries underflow to 0. out[n] = (V[n] + sum w_m V[m]) / (1 + sum w_m)
// LDS kept small (6.3 KB) -> 16 blocks/CU = 32 waves/CU for latency hiding.
__global__ void __launch_bounds__(128) sparse_attn(
    const unsigned int* __restrict__ mask, const float* __restrict__ Q0,
    const float* __restrict__ K0, const float* __restrict__ V,
    float* __restrict__ out) {
    int n = blockIdx.x;
    int t = threadIdx.x;                             // 0..127
    __shared__ int   midx[MAXE];
    __shared__ float wts[MAXE];
    __shared__ int   cnt;
    __shared__ float q0s[32];
    if (t == 0) cnt = 0;
    if (t < 32) q0s[t] = Q0[n * 32 + t];
    __syncthreads();

    // phase 1: thread t scans mask word t (columns t*32 .. t*32+31)
    unsigned int w = mask[n * 128 + t];
    while (w) {
        int b = __ffs(w) - 1;
        w &= w - 1;
        int m = t * 32 + b;
        const float4* kp = (const float4*)(K0 + m * 32);
        float s = 0.f;
#pragma unroll
        for (int i = 0; i < 8; ++i) {
            float4 kv = kp[i];
            s += q0s[i * 4 + 0] * kv.x + q0s[i * 4 + 1] * kv.y +
                 q0s[i * 4 + 2] * kv.z + q0s[i * 4 + 3] * kv.w;
        }
        float wt = __expf(s * TEMP - 1.0f);
        int pos = atomicAdd(&cnt, 1);
        if (pos < MAXE) { midx[pos] = m; wts[pos] = wt; }
    }
    __syncthreads();

    // phase 2: thread t owns channel t; batch 4 edges/iter to overlap L2 loads
    int c = min(cnt, MAXE);
    float acc  = V[n * 128 + t];                     // diagonal, weight e^0 = 1
    float wsum = 1.0f;
    int e = 0;
    for (; e + 4 <= c; e += 4) {
        float w0 = wts[e],  w1 = wts[e + 1], w2 = wts[e + 2], w3 = wts[e + 3];
        int   m0 = midx[e], m1 = midx[e + 1], m2 = midx[e + 2], m3 = midx[e + 3];
        float v0 = V[m0 * 128 + t];
        float v1 = V[m1 * 128 + t];
        float v2 = V[m2 * 128 + t];
        float v3 = V[m3 * 128 + t];
        acc  += w0 * v0 + w1 * v1 + w2 * v2 + w3 * v3;
        wsum += w0 + w1 + w2 + w3;
    }
    for (; e < c; ++e) {
        float wt = wts[e];
        acc  += wt * V[midx[e] * 128 + t];
        wsum += wt;
    }
    out[n * 128 + t] = acc / wsum;
}

// ---------------- K5: final = attn_out @ w_out + b_out, node-major ---------
// final[n][c] stored with coalesced float4 writes (gather transposes later).
__global__ void out_gemm(const float* __restrict__ ain, const float* __restrict__ wout,
                         const float* __restrict__ bout, float* __restrict__ final) {
    int gid = blockIdx.x * blockDim.x + threadIdx.x; // 4096*32
    int g = gid & 31;                                // col group (4 cols)
    int n = gid >> 5;
    const float* arow = ain + n * 128;
    float4 acc = {0.f, 0.f, 0.f, 0.f};
#pragma unroll 8
    for (int d = 0; d < 128; ++d) {
        float a = arow[d];
        float4 w = *(const float4*)(wout + d * 128 + g * 4);
        acc.x += a * w.x; acc.y += a * w.y; acc.z += a * w.z; acc.w += a * w.w;
    }
    float4 b = *(const float4*)(bout + g * 4);
    acc.x += b.x; acc.y += b.y; acc.z += b.z; acc.w += b.w;
    *(float4*)(final + n * 128 + g * 4) = acc;
}

// ---------------- K6: pixel gather via LDS transpose -----------------------
// out[c][p] = final[seg[p]][c]. Block: 64 pixels x 128 channels.
// Phase A: coalesced node-row reads (256 B/wave) -> padded LDS tile.
// Phase B: coalesced pixel-contiguous writes per channel.
#define GT_PIX 64
__global__ void __launch_bounds__(256) gather_out(
    const float* __restrict__ final, const int* __restrict__ seg,
    float* __restrict__ out) {
    __shared__ float tile[GT_PIX][129];              // +1 pad: conflict-free both phases
    __shared__ int   sseg[GT_PIX];
    int base = blockIdx.x * GT_PIX;
    int t = threadIdx.x;
    if (t < GT_PIX) sseg[t] = seg[base + t];
    __syncthreads();

    int c  = t & 127;                                // phase A: 2 pixels/pass
    int pl = t >> 7;
#pragma unroll 8
    for (int p = pl; p < GT_PIX; p += 2)
        tile[p][c] = final[sseg[p] * 128 + c];
    __syncthreads();

    int j  = t & 63;                                 // phase B: 4 channels/pass
    int c0 = t >> 6;
#pragma unroll 8
    for (int cc = c0; cc < 128; cc += 4)
        out[cc * (HW * HW) + base + j] = tile[j][cc];
}

extern "C" void kernel_launch(void* const* d_in, const int* in_sizes, int n_in,
                              void* d_out, int out_size, void* d_ws, size_t ws_size,
                              hipStream_t stream) {
    const float* spf  = (const float*)d_in[0];   // (128, 4096)
    const int*   seg  = (const int*)d_in[1];     // (512, 512)
    const float* wqkv = (const float*)d_in[2];   // (128, 384)
    const float* wout = (const float*)d_in[3];   // (128, 128)
    const float* bout = (const float*)d_in[4];   // (128,)
    float* out = (float*)d_out;                  // (1,128,512,512)

    char* ws = (char*)d_ws;                      // needs 9 MB
    unsigned int* mask = (unsigned int*)ws;                     // 2 MB
    float* Q0    = (float*)(ws + (2u << 20));                   // 512 KB
    float* K0    = (float*)(ws + (2u << 20) + (512u << 10));    // 512 KB
    float* V     = (float*)(ws + (3u << 20));                   // 2 MB
    float* aout  = (float*)(ws + (5u << 20));                   // 2 MB
    float* final = (float*)(ws + (7u << 20));                   // 2 MB

    hipLaunchKernelGGL(zero_mask,  dim3(512),  dim3(256), 0, stream, mask);
    hipLaunchKernelGGL(build_adj,  dim3((510 * 510 + 255) / 256), dim3(256), 0, stream, seg, mask);
    hipLaunchKernelGGL(qkv_gemm,   dim3(768),  dim3(256), 0, stream, spf, wqkv, Q0, K0, V);
    hipLaunchKernelGGL(l2norm_qk,  dim3(32),   dim3(256), 0, stream, Q0, K0);
    hipLaunchKernelGGL(sparse_attn, dim3(4096), dim3(128), 0, stream, mask, Q0, K0, V, aout);
    hipLaunchKernelGGL(out_gemm,   dim3(512),  dim3(256), 0, stream, aout, wout, bout, final);
    hipLaunchKernelGGL(gather_out, dim3((HW * HW) / GT_PIX), dim3(256), 0, stream, final, seg, out);
}

// Round 3
// 221.414 us; speedup vs baseline: 1.2179x; 1.0910x over previous
//
#include <hip/hip_runtime.h>

#define NSP 4096
#define HW 512
#define TEMP 0.08838834764831845f  // 128^-0.5
#define MAXE 768                   // max distinct neighbors/node (<=~260 by count bound)
#define ADJ_BLOCKS 1017            // ceil(510*510/256)
#define QKV_BLOCKS 768             // 4096*48/256

// ---------------- K1: fused adjacency-build + QKV GEMM (+l2norm) -----------
// blocks [0, ADJ_BLOCKS): build adjacency bitmask from 2x2 windows
// blocks [ADJ_BLOCKS, +QKV_BLOCKS): packed QKV GEMM with fused q/k l2-norm
__global__ void __launch_bounds__(256) adj_qkv(
    const int* __restrict__ seg, unsigned int* __restrict__ mask,
    const float* __restrict__ spf, const float* __restrict__ wqkv,
    float* __restrict__ Q0, float* __restrict__ K0, float* __restrict__ V) {
    int t = threadIdx.x;
    if (blockIdx.x < ADJ_BLOCKS) {
        int idx = blockIdx.x * 256 + t;
        if (idx >= 510 * 510) return;
        int i = idx / 510, j = idx - i * 510;
        const int* r = seg + i * HW + j;
        int a = r[0], b = r[1], c = r[HW], d = r[HW + 1];
        int mx = max(max(a, b), max(c, d));
        int mn = min(min(a, b), min(c, d));
        if (mx == mn) return;                        // diagonal zeroed in ref
        atomicOr(&mask[mx * 128 + (mn >> 5)], 1u << (mn & 31));
        atomicOr(&mask[mn * 128 + (mx >> 5)], 1u << (mx & 31));
        return;
    }
    // ---- QKV: x = spf^T (4096x128); need q head0, k head0, all of v ----
    int gid = (blockIdx.x - ADJ_BLOCKS) * 256 + t;   // 0 .. 4096*48-1
    int g = gid % 48;
    int n = gid / 48;
    int wcol;
    float* outp;
    if (g < 8)       { wcol = g * 4;              outp = Q0 + n * 32  + g * 4; }
    else if (g < 16) { wcol = 128 + (g - 8) * 4;  outp = K0 + n * 32  + (g - 8) * 4; }
    else             { wcol = 256 + (g - 16) * 4; outp = V  + n * 128 + (g - 16) * 4; }
    float4 acc = {0.f, 0.f, 0.f, 0.f};
#pragma unroll 8
    for (int d = 0; d < 128; ++d) {
        float x = spf[d * NSP + n];                  // x[n][d] = spf[d][n]
        float4 w = *(const float4*)(wqkv + d * 384 + wcol);
        acc.x += x * w.x; acc.y += x * w.y; acc.z += x * w.z; acc.w += x * w.w;
    }
    if (g < 16) {
        // the 8 q-threads (and 8 k-threads) of node n are 8-aligned in one wave:
        // n*48 mod 64 in {0,16,32,48} -> q at lane base {0,16,32,48}, k at +8.
        float s = acc.x * acc.x + acc.y * acc.y + acc.z * acc.z + acc.w * acc.w;
        s += __shfl_xor(s, 1);
        s += __shfl_xor(s, 2);
        s += __shfl_xor(s, 4);
        float inv = 1.0f / fmaxf(sqrtf(s), 1e-12f);
        acc.x *= inv; acc.y *= inv; acc.z *= inv; acc.w *= inv;
    }
    *(float4*)outp = acc;
}

// ---------------- K2: sparse masked softmax-attention ----------------------
// one block (128 thr) per node n. Diagonal score is exactly 1.0 = row max;
// masked entries underflow to 0. out[n] = (V[n] + sum w_m V[m]) / (1 + sum w_m)
// Phase 1 load-balanced via prefix-scan over mask-word popcounts.
__global__ void __launch_bounds__(128) sparse_attn(
    const unsigned int* __restrict__ mask, const float* __restrict__ Q0,
    const float* __restrict__ K0, const float* __restrict__ V,
    float* __restrict__ out) {
    int n = blockIdx.x;
    int t = threadIdx.x;                             // 0..127
    __shared__ unsigned int words[128];
    __shared__ int   pfx[128];                       // inclusive scan
    __shared__ int   midx[MAXE];
    __shared__ float wts[MAXE];
    __shared__ float q0s[32];
    __shared__ float4 redv[4][32];
    __shared__ float  redw[4];

    unsigned int w = mask[n * 128 + t];
    words[t] = w;
    if (t < 32) q0s[t] = Q0[n * 32 + t];
    pfx[t] = __popc(w);
    __syncthreads();
#pragma unroll
    for (int off = 1; off < 128; off <<= 1) {        // Hillis-Steele scan
        int v = pfx[t];
        int add = (t >= off) ? pfx[t - off] : 0;
        __syncthreads();
        pfx[t] = v + add;
        __syncthreads();
    }
    int E = min(pfx[127], MAXE);

    // phase 1: evenly-distributed edge extraction + score
    for (int e = t; e < E; e += 128) {
        int lo = 0, hi = 127;                        // first word with pfx > e
        while (lo < hi) { int mid = (lo + hi) >> 1; if (pfx[mid] > e) hi = mid; else lo = mid + 1; }
        int base = (lo > 0) ? pfx[lo - 1] : 0;
        int r = e - base;
        unsigned int x = words[lo];
        for (int i = 0; i < r; ++i) x &= x - 1;      // r-th set bit
        int m = lo * 32 + (__ffs(x) - 1);
        const float4* kp = (const float4*)(K0 + m * 32);
        float s = 0.f;
#pragma unroll
        for (int i = 0; i < 8; ++i) {
            float4 kv = kp[i];
            s += q0s[i * 4 + 0] * kv.x + q0s[i * 4 + 1] * kv.y +
                 q0s[i * 4 + 2] * kv.z + q0s[i * 4 + 3] * kv.w;
        }
        wts[e]  = __expf(s * TEMP - 1.0f);
        midx[e] = m;
    }
    __syncthreads();

    // phase 2: thread = (edge-group eg, 4-channel group cg); float4 V rows
    int cg = t & 31, eg = t >> 5;
    const float4* V4 = (const float4*)V;
    float4 acc = {0.f, 0.f, 0.f, 0.f};
    float wp = 0.f;
    for (int e = eg; e < E; e += 4) {
        float wt = wts[e];
        float4 v = V4[midx[e] * 32 + cg];
        acc.x += wt * v.x; acc.y += wt * v.y; acc.z += wt * v.z; acc.w += wt * v.w;
        wp += wt;
    }
    redv[eg][cg] = acc;
    if (cg == 0) redw[eg] = wp;
    __syncthreads();
    if (t < 32) {
        float4 a0 = redv[0][t], a1 = redv[1][t], a2 = redv[2][t], a3 = redv[3][t];
        float ws = 1.0f + redw[0] + redw[1] + redw[2] + redw[3];
        float4 vd = V4[n * 32 + t];                  // diagonal, weight e^0 = 1
        float inv = 1.0f / ws;
        float4 o;
        o.x = (a0.x + a1.x + a2.x + a3.x + vd.x) * inv;
        o.y = (a0.y + a1.y + a2.y + a3.y + vd.y) * inv;
        o.z = (a0.z + a1.z + a2.z + a3.z + vd.z) * inv;
        o.w = (a0.w + a1.w + a2.w + a3.w + vd.w) * inv;
        ((float4*)out)[n * 32 + t] = o;
    }
}

// ---------------- K3: final = attn_out @ w_out + b_out, node-major ---------
__global__ void out_gemm(const float* __restrict__ ain, const float* __restrict__ wout,
                         const float* __restrict__ bout, float* __restrict__ final) {
    int gid = blockIdx.x * blockDim.x + threadIdx.x; // 4096*32
    int g = gid & 31;                                // col group (4 cols)
    int n = gid >> 5;
    const float* arow = ain + n * 128;
    float4 acc = {0.f, 0.f, 0.f, 0.f};
#pragma unroll 8
    for (int d = 0; d < 128; ++d) {
        float a = arow[d];
        float4 w = *(const float4*)(wout + d * 128 + g * 4);
        acc.x += a * w.x; acc.y += a * w.y; acc.z += a * w.z; acc.w += a * w.w;
    }
    float4 b = *(const float4*)(bout + g * 4);
    acc.x += b.x; acc.y += b.y; acc.z += b.z; acc.w += b.w;
    *(float4*)(final + n * 128 + g * 4) = acc;
}

// ---------------- K4: pixel gather via LDS transpose, float4 both sides ----
// out[c][p] = final[seg[p]][c]. Block: 64 pixels x 128 channels.
#define GT_PIX 64
__global__ void __launch_bounds__(256) gather_out(
    const float* __restrict__ final, const int* __restrict__ seg,
    float* __restrict__ out) {
    __shared__ __align__(16) float tile[GT_PIX][132]; // stride 132: 16B-aligned rows
    __shared__ int sseg[GT_PIX];
    int base = blockIdx.x * GT_PIX;
    int t = threadIdx.x;
    if (t < GT_PIX) sseg[t] = seg[base + t];
    __syncthreads();

    // phase A: 1 KB/wave float4 reads of node rows -> LDS
    int c4 = t & 31, pp = t >> 5;                    // 8 pixels per pass
    const float4* f4 = (const float4*)final;
#pragma unroll
    for (int i = 0; i < 8; ++i) {
        int p = pp + 8 * i;
        float4 v = f4[sseg[p] * 32 + c4];
        *(float4*)&tile[p][c4 * 4] = v;
    }
    __syncthreads();

    // phase B: pack 4 pixels/channel -> 1 KB/wave float4 stores (2-way banks)
    int jp = t >> 4;                                 // pixel quad 4*jp..4*jp+3
    int cg = t & 15;
#pragma unroll
    for (int pass = 0; pass < 8; ++pass) {
        int cc = cg + 16 * pass;
        float4 v;
        v.x = tile[4 * jp + 0][cc];
        v.y = tile[4 * jp + 1][cc];
        v.z = tile[4 * jp + 2][cc];
        v.w = tile[4 * jp + 3][cc];
        *(float4*)(out + (size_t)cc * (HW * HW) + base + 4 * jp) = v;
    }
}

extern "C" void kernel_launch(void* const* d_in, const int* in_sizes, int n_in,
                              void* d_out, int out_size, void* d_ws, size_t ws_size,
                              hipStream_t stream) {
    const float* spf  = (const float*)d_in[0];   // (128, 4096)
    const int*   seg  = (const int*)d_in[1];     // (512, 512)
    const float* wqkv = (const float*)d_in[2];   // (128, 384)
    const float* wout = (const float*)d_in[3];   // (128, 128)
    const float* bout = (const float*)d_in[4];   // (128,)
    float* out = (float*)d_out;                  // (1,128,512,512)

    char* ws = (char*)d_ws;                      // needs 9 MB
    unsigned int* mask = (unsigned int*)ws;                     // 2 MB
    float* Q0    = (float*)(ws + (2u << 20));                   // 512 KB
    float* K0    = (float*)(ws + (2u << 20) + (512u << 10));    // 512 KB
    float* V     = (float*)(ws + (3u << 20));                   // 2 MB
    float* aout  = (float*)(ws + (5u << 20));                   // 2 MB
    float* final = (float*)(ws + (7u << 20));                   // 2 MB

    hipMemsetAsync(mask, 0, NSP * 128 * sizeof(unsigned int), stream);
    hipLaunchKernelGGL(adj_qkv, dim3(ADJ_BLOCKS + QKV_BLOCKS), dim3(256), 0, stream,
                       seg, mask, spf, wqkv, Q0, K0, V);
    hipLaunchKernelGGL(sparse_attn, dim3(4096), dim3(128), 0, stream, mask, Q0, K0, V, aout);
    hipLaunchKernelGGL(out_gemm,   dim3(512),  dim3(256), 0, stream, aout, wout, bout, final);
    hipLaunchKernelGGL(gather_out, dim3((HW * HW) / GT_PIX), dim3(256), 0, stream, final, seg, out);
}

// Round 4
// 215.289 us; speedup vs baseline: 1.2525x; 1.0284x over previous
//
#include <hip/hip_runtime.h>

#define NSP 4096
#define HW 512
#define TEMP 0.08838834764831845f  // 128^-0.5
#define MAXE 640                   // max neighbors/node (theoretical bound ~390)
#define PREP_ZERO 512              // blocks zeroing mask (512*256 uint4 = 2 MB)
#define PREP_WF 64                 // blocks computing Wfused (64*256 = 16384 = 128*128)
#define ADJ_BLOCKS 1017            // ceil(510*510/256)
#define QKV_BLOCKS 768             // 4096*48/256

// ---------------- K0: prep = zero adjacency mask || Wfused = Wv @ Wout -----
__global__ void __launch_bounds__(256) prep(
    unsigned int* __restrict__ mask, const float* __restrict__ wqkv,
    const float* __restrict__ wout, float* __restrict__ Wf) {
    int t = threadIdx.x;
    if (blockIdx.x < PREP_ZERO) {
        ((uint4*)mask)[blockIdx.x * 256 + t] = make_uint4(0u, 0u, 0u, 0u);
        return;
    }
    int gid = (blockIdx.x - PREP_ZERO) * 256 + t;    // (d,c) of Wfused
    int d = gid >> 7, c = gid & 127;
    float acc = 0.f;
#pragma unroll 8
    for (int k = 0; k < 128; ++k)
        acc += wqkv[d * 384 + 256 + k] * wout[k * 128 + c];
    Wf[d * 128 + c] = acc;
}

// ---------------- K1: fused adjacency-build + Q/K/V' GEMM (+l2norm) --------
// blocks [0, ADJ_BLOCKS): adjacency bitmask from 2x2 windows
// blocks [ADJ_BLOCKS, +QKV_BLOCKS): q head0, k head0 (l2-normed), V' = x@Wf
__global__ void __launch_bounds__(256) adj_qkv(
    const int* __restrict__ seg, unsigned int* __restrict__ mask,
    const float* __restrict__ spf, const float* __restrict__ wqkv,
    const float* __restrict__ Wf,
    float* __restrict__ Q0, float* __restrict__ K0, float* __restrict__ V) {
    int t = threadIdx.x;
    if (blockIdx.x < ADJ_BLOCKS) {
        int idx = blockIdx.x * 256 + t;
        if (idx >= 510 * 510) return;
        int i = idx / 510, j = idx - i * 510;
        const int* r = seg + i * HW + j;
        int a = r[0], b = r[1], c = r[HW], d = r[HW + 1];
        int mx = max(max(a, b), max(c, d));
        int mn = min(min(a, b), min(c, d));
        if (mx == mn) return;                        // diagonal zeroed in ref
        atomicOr(&mask[mx * 128 + (mn >> 5)], 1u << (mn & 31));
        atomicOr(&mask[mn * 128 + (mx >> 5)], 1u << (mx & 31));
        return;
    }
    int gid = (blockIdx.x - ADJ_BLOCKS) * 256 + t;   // 0 .. 4096*48-1
    int g = gid % 48;
    int n = gid / 48;
    const float* wbase;
    int wstride;
    float* outp;
    if (g < 8)       { wbase = wqkv + g * 4;               wstride = 384; outp = Q0 + n * 32  + g * 4; }
    else if (g < 16) { wbase = wqkv + 128 + (g - 8) * 4;   wstride = 384; outp = K0 + n * 32  + (g - 8) * 4; }
    else             { wbase = Wf + (g - 16) * 4;          wstride = 128; outp = V  + n * 128 + (g - 16) * 4; }
    float4 acc = {0.f, 0.f, 0.f, 0.f};
#pragma unroll 8
    for (int d = 0; d < 128; ++d) {
        float x = spf[d * NSP + n];                  // x[n][d] = spf[d][n]
        float4 w = *(const float4*)(wbase + d * wstride);
        acc.x += x * w.x; acc.y += x * w.y; acc.z += x * w.z; acc.w += x * w.w;
    }
    if (g < 16) {
        // 8 q-threads (8 k-threads) of node n are 8-aligned within one wave:
        // n*48 mod 64 in {0,16,32,48}.
        float s = acc.x * acc.x + acc.y * acc.y + acc.z * acc.z + acc.w * acc.w;
        s += __shfl_xor(s, 1);
        s += __shfl_xor(s, 2);
        s += __shfl_xor(s, 4);
        float inv = 1.0f / fmaxf(sqrtf(s), 1e-12f);
        acc.x *= inv; acc.y *= inv; acc.z *= inv; acc.w *= inv;
    }
    *(float4*)outp = acc;
}

// ---------------- K2: sparse attention -> FINAL node table -----------------
// one block (128 thr) per node n. Diagonal score is exactly 1.0 = row max;
// masked entries underflow to 0. final[n] = (V'[n] + sum w_m V'[m])/(1+sum w_m) + b
__global__ void __launch_bounds__(128) sparse_attn(
    const unsigned int* __restrict__ mask, const float* __restrict__ Q0,
    const float* __restrict__ K0, const float* __restrict__ V,
    const float* __restrict__ bout, float* __restrict__ final) {
    int n = blockIdx.x;
    int t = threadIdx.x;                             // 0..127
    int lane = t & 63, wid = t >> 6;
    __shared__ unsigned int words[128];
    __shared__ int   pfx[128];                       // inclusive scan of popcounts
    __shared__ int   midx[MAXE];
    __shared__ float wts[MAXE];
    __shared__ float q0s[32];
    __shared__ float4 redv[4][32];
    __shared__ float  redw[4];

    unsigned int w = mask[n * 128 + t];
    words[t] = w;
    if (t < 32) q0s[t] = Q0[n * 32 + t];

    // wave-level inclusive scan of popcounts (6 shuffles), then combine waves
    int p = __popc(w);
#pragma unroll
    for (int off = 1; off < 64; off <<= 1) {
        int y = __shfl_up(p, off);
        if (lane >= off) p += y;
    }
    pfx[t] = p;
    __syncthreads();
    if (wid == 1) pfx[t] = p + pfx[63];
    __syncthreads();
    int E = min(pfx[127], MAXE);

    // phase 1: evenly-distributed edge extraction + score
    for (int e = t; e < E; e += 128) {
        int lo = 0, hi = 127;                        // first word with pfx > e
        while (lo < hi) { int mid = (lo + hi) >> 1; if (pfx[mid] > e) hi = mid; else lo = mid + 1; }
        int base = (lo > 0) ? pfx[lo - 1] : 0;
        int r = e - base;
        unsigned int x = words[lo];
        for (int i = 0; i < r; ++i) x &= x - 1;      // r-th set bit
        int m = lo * 32 + (__ffs(x) - 1);
        const float4* kp = (const float4*)(K0 + m * 32);
        float s = 0.f;
#pragma unroll
        for (int i = 0; i < 8; ++i) {
            float4 kv = kp[i];
            s += q0s[i * 4 + 0] * kv.x + q0s[i * 4 + 1] * kv.y +
                 q0s[i * 4 + 2] * kv.z + q0s[i * 4 + 3] * kv.w;
        }
        wts[e]  = __expf(s * TEMP - 1.0f);
        midx[e] = m;
    }
    __syncthreads();

    // phase 2: thread = (edge-group eg, 4-channel group cg); two independent
    // edge streams -> 2 outstanding L2 loads per thread
    int cg = t & 31, eg = t >> 5;
    const float4* V4 = (const float4*)V;
    float4 acc = {0.f, 0.f, 0.f, 0.f};
    float wp = 0.f;
    int e = eg;
    for (; e + 4 < E; e += 8) {
        float wa = wts[e];     int ma = midx[e];
        float wb = wts[e + 4]; int mb = midx[e + 4];
        float4 va = V4[ma * 32 + cg];
        float4 vb = V4[mb * 32 + cg];
        acc.x += wa * va.x + wb * vb.x;
        acc.y += wa * va.y + wb * vb.y;
        acc.z += wa * va.z + wb * vb.z;
        acc.w += wa * va.w + wb * vb.w;
        wp += wa + wb;
    }
    for (; e < E; e += 4) {
        float wt = wts[e];
        float4 v = V4[midx[e] * 32 + cg];
        acc.x += wt * v.x; acc.y += wt * v.y; acc.z += wt * v.z; acc.w += wt * v.w;
        wp += wt;
    }
    redv[eg][cg] = acc;
    if (cg == 0) redw[eg] = wp;
    __syncthreads();
    if (t < 32) {
        float4 a0 = redv[0][t], a1 = redv[1][t], a2 = redv[2][t], a3 = redv[3][t];
        float ws = 1.0f + redw[0] + redw[1] + redw[2] + redw[3];
        float4 vd = V4[n * 32 + t];                  // diagonal, weight e^0 = 1
        float4 bb = ((const float4*)bout)[t];        // bias: softmax rows sum to 1
        float inv = 1.0f / ws;
        float4 o;
        o.x = (a0.x + a1.x + a2.x + a3.x + vd.x) * inv + bb.x;
        o.y = (a0.y + a1.y + a2.y + a3.y + vd.y) * inv + bb.y;
        o.z = (a0.z + a1.z + a2.z + a3.z + vd.z) * inv + bb.z;
        o.w = (a0.w + a1.w + a2.w + a3.w + vd.w) * inv + bb.w;
        ((float4*)final)[n * 32 + t] = o;
    }
}

// ---------------- K3: pixel gather via LDS transpose, float4 both sides ----
// out[c][p] = final[seg[p]][c]. Block: 64 pixels x 128 channels.
#define GT_PIX 64
__global__ void __launch_bounds__(256) gather_out(
    const float* __restrict__ final, const int* __restrict__ seg,
    float* __restrict__ out) {
    __shared__ __align__(16) float tile[GT_PIX][132]; // stride 132: 16B-aligned rows
    __shared__ int sseg[GT_PIX];
    int base = blockIdx.x * GT_PIX;
    int t = threadIdx.x;
    if (t < GT_PIX) sseg[t] = seg[base + t];
    __syncthreads();

    // phase A: 1 KB/wave float4 reads of node rows -> LDS
    int c4 = t & 31, pp = t >> 5;
    const float4* f4 = (const float4*)final;
#pragma unroll
    for (int i = 0; i < 8; ++i) {
        int p = pp + 8 * i;
        float4 v = f4[sseg[p] * 32 + c4];
        *(float4*)&tile[p][c4 * 4] = v;
    }
    __syncthreads();

    // phase B: pack 4 pixels/channel -> 1 KB/wave float4 stores
    int jp = t >> 4;                                 // pixel quad 4*jp..4*jp+3
    int cg = t & 15;
#pragma unroll
    for (int pass = 0; pass < 8; ++pass) {
        int cc = cg + 16 * pass;
        float4 v;
        v.x = tile[4 * jp + 0][cc];
        v.y = tile[4 * jp + 1][cc];
        v.z = tile[4 * jp + 2][cc];
        v.w = tile[4 * jp + 3][cc];
        *(float4*)(out + (size_t)cc * (HW * HW) + base + 4 * jp) = v;
    }
}

extern "C" void kernel_launch(void* const* d_in, const int* in_sizes, int n_in,
                              void* d_out, int out_size, void* d_ws, size_t ws_size,
                              hipStream_t stream) {
    const float* spf  = (const float*)d_in[0];   // (128, 4096)
    const int*   seg  = (const int*)d_in[1];     // (512, 512)
    const float* wqkv = (const float*)d_in[2];   // (128, 384)
    const float* wout = (const float*)d_in[3];   // (128, 128)
    const float* bout = (const float*)d_in[4];   // (128,)
    float* out = (float*)d_out;                  // (1,128,512,512)

    char* ws = (char*)d_ws;                      // needs ~7.1 MB
    unsigned int* mask = (unsigned int*)ws;                     // 2 MB
    float* Q0    = (float*)(ws + (2u << 20));                   // 512 KB
    float* K0    = (float*)(ws + (2u << 20) + (512u << 10));    // 512 KB
    float* V     = (float*)(ws + (3u << 20));                   // 2 MB (= x @ Wfused)
    float* final = (float*)(ws + (5u << 20));                   // 2 MB
    float* Wf    = (float*)(ws + (7u << 20));                   // 64 KB

    hipLaunchKernelGGL(prep, dim3(PREP_ZERO + PREP_WF), dim3(256), 0, stream,
                       mask, wqkv, wout, Wf);
    hipLaunchKernelGGL(adj_qkv, dim3(ADJ_BLOCKS + QKV_BLOCKS), dim3(256), 0, stream,
                       seg, mask, spf, wqkv, Wf, Q0, K0, V);
    hipLaunchKernelGGL(sparse_attn, dim3(4096), dim3(128), 0, stream,
                       mask, Q0, K0, V, bout, final);
    hipLaunchKernelGGL(gather_out, dim3((HW * HW) / GT_PIX), dim3(256), 0, stream,
                       final, seg, out);
}